// Round 21
// baseline (75.065 us; speedup 1.0000x reference)
//
#include <hip/hip_runtime.h>
#include <math.h>

static constexpr int B_  = 4;
static constexpr int TQ  = 128;
static constexpr int TK  = 512;
static constexpr int NN  = 1024;
static constexpr int QS  = 1024;
static constexpr int VS  = 1024;
static constexpr int OS  = 1024;

#define K2F    2.8853900817779268f   // 2*log2(e)
#define LOG2EF 1.4426950408889634f
#define SLICE  524288                // 512*1024

typedef __attribute__((ext_vector_type(8))) short bf16x8;
typedef __attribute__((ext_vector_type(4))) float f32x4;

#define MFMA16(a,b,c) __builtin_amdgcn_mfma_f32_16x16x32_bf16((a),(b),(c),0,0,0)

__device__ __forceinline__ ushort bf16_rne(float x) {
    uint u = __float_as_uint(x);
    u += 0x7FFFu + ((u >> 16) & 1u);
    return (ushort)(u >> 16);
}
__device__ __forceinline__ float bf16_to_f(ushort h) {
    return __uint_as_float((uint)h << 16);
}
__device__ __forceinline__ void split2(float x, ushort& h, ushort& l) {
    ushort hh = bf16_rne(x);
    float hv = __uint_as_float((uint)hh << 16);
    h = hh;
    l = bf16_rne(x - hv);
}

// ---------------------------------------------------------------------------
// [1] conversion: Q -> hi/lo, Wq -> hi, Wout -> hi, V transpose -> hi only
// ---------------------------------------------------------------------------
__global__ __launch_bounds__(256) void cvt_all_kernel(
    const float* __restrict__ Q, const float* __restrict__ Wq,
    const float* __restrict__ Wo, const float* __restrict__ V,
    ushort* __restrict__ Qh, ushort* __restrict__ Ql,
    ushort* __restrict__ Wqh,
    ushort* __restrict__ Woh,
    ushort* __restrict__ Vth)
{
    __shared__ float tile[64][65];
    const int bid = blockIdx.x;
    const int t = threadIdx.x;
    if (bid < 3584) {
        if (bid < 512) {
            int idx = bid*256 + t;
            float4 v = ((const float4*)Q)[idx];
            ushort4 hh, ll;
            split2(v.x, hh.x, ll.x); split2(v.y, hh.y, ll.y);
            split2(v.z, hh.z, ll.z); split2(v.w, hh.w, ll.w);
            ((ushort4*)Qh)[idx] = hh;
            ((ushort4*)Ql)[idx] = ll;
        } else {
            const float* src; ushort* h; int idx;
            if (bid < 1536) { src = Wq; h = Wqh; idx = (bid-512)*256 + t; }
            else            { src = Wo; h = Woh; idx = (bid-1536)*256 + t; }
            float4 v = ((const float4*)src)[idx];
            ushort4 hh;
            hh.x = bf16_rne(v.x); hh.y = bf16_rne(v.y);
            hh.z = bf16_rne(v.z); hh.w = bf16_rne(v.w);
            ((ushort4*)h)[idx] = hh;
        }
        return;
    }
    const int vid = bid - 3584;
    const int v0 = (vid & 15) * 64;
    const int k0 = ((vid >> 4) & 7) * 64;
    const int b  = vid >> 7;
    const float* src = V + ((size_t)b*TK + k0)*VS + v0;
    #pragma unroll
    for (int p = 0; p < 4; ++p) {
        int r = (t >> 4) + p*16, c = (t & 15) * 4;
        float4 vv = *(const float4*)(src + (size_t)r*VS + c);
        tile[r][c] = vv.x; tile[r][c+1] = vv.y; tile[r][c+2] = vv.z; tile[r][c+3] = vv.w;
    }
    __syncthreads();
    ushort* dh = Vth + (size_t)b*(VS*TK) + (size_t)v0*TK + k0;
    #pragma unroll
    for (int p = 0; p < 4; ++p) {
        int vr = (t >> 4) + p*16, kc = (t & 15) * 4;
        ushort4 hh;
        hh.x = bf16_rne(tile[kc+0][vr]);
        hh.y = bf16_rne(tile[kc+1][vr]);
        hh.z = bf16_rne(tile[kc+2][vr]);
        hh.w = bf16_rne(tile[kc+3][vr]);
        *(ushort4*)(dh + (size_t)vr*TK + kc) = hh;
    }
}

// ---------------------------------------------------------------------------
// [2] 2-MFMA NT GEMM (A hi/lo, B hi only), M=512. A-GEMM. K-split 4.
// ---------------------------------------------------------------------------
__global__ __launch_bounds__(256) void mfma_nt2_kernel(
    const ushort* __restrict__ Ah, const ushort* __restrict__ Al,
    const ushort* __restrict__ Bh,
    float* __restrict__ Cp, int lda, int ldb, int Nout, int kchunk, int bstride)
{
    __shared__ alignas(16) ushort lA[2][64][40];
    __shared__ alignas(16) ushort lB[64][40];
    const int t = threadIdx.x;
    const int m0 = blockIdx.y * 64, n0 = blockIdx.x * 64, kz = blockIdx.z;
    const int k0 = kz * kchunk;
    const int batch = m0 >> 7;
    const ushort* bhp = Bh + (size_t)batch * bstride;
    const int srow = t >> 2, skc = (t & 3) * 8;
    const int lane = t & 63, w = t >> 6;
    const int wm = (w >> 1) * 32, wn = (w & 1) * 32;
    const int fr = lane & 15, fg = (lane >> 4) * 8;

    f32x4 acc00 = {0,0,0,0}, acc01 = {0,0,0,0}, acc10 = {0,0,0,0}, acc11 = {0,0,0,0};

    for (int kb = k0; kb < k0 + kchunk; kb += 32) {
        *(uint4*)&lA[0][srow][skc] = *(const uint4*)(Ah  + (size_t)(m0+srow)*lda + kb + skc);
        *(uint4*)&lA[1][srow][skc] = *(const uint4*)(Al  + (size_t)(m0+srow)*lda + kb + skc);
        *(uint4*)&lB[srow][skc]    = *(const uint4*)(bhp + (size_t)(n0+srow)*ldb + kb + skc);
        __syncthreads();
        bf16x8 ah0 = *(const bf16x8*)&lA[0][wm + fr     ][fg];
        bf16x8 ah1 = *(const bf16x8*)&lA[0][wm + 16 + fr][fg];
        bf16x8 al0 = *(const bf16x8*)&lA[1][wm + fr     ][fg];
        bf16x8 al1 = *(const bf16x8*)&lA[1][wm + 16 + fr][fg];
        bf16x8 bh0 = *(const bf16x8*)&lB[wn + fr     ][fg];
        bf16x8 bh1 = *(const bf16x8*)&lB[wn + 16 + fr][fg];
        acc00 = MFMA16(ah0, bh0, acc00);
        acc00 = MFMA16(al0, bh0, acc00);
        acc01 = MFMA16(ah0, bh1, acc01);
        acc01 = MFMA16(al0, bh1, acc01);
        acc10 = MFMA16(ah1, bh0, acc10);
        acc10 = MFMA16(al1, bh0, acc10);
        acc11 = MFMA16(ah1, bh1, acc11);
        acc11 = MFMA16(al1, bh1, acc11);
        __syncthreads();
    }
    float* o = Cp + (size_t)kz * 512 * Nout;
    const int orow = (lane >> 4) * 4;
    #pragma unroll
    for (int r2 = 0; r2 < 4; ++r2) {
        o[(size_t)(m0+wm+orow+r2)*Nout      + n0+wn+fr]      = acc00[r2];
        o[(size_t)(m0+wm+orow+r2)*Nout      + n0+wn+16+fr]   = acc01[r2];
        o[(size_t)(m0+wm+16+orow+r2)*Nout   + n0+wn+fr]      = acc10[r2];
        o[(size_t)(m0+wm+16+orow+r2)*Nout   + n0+wn+16+fr]   = acc11[r2];
    }
}

// ---------------------------------------------------------------------------
// [6] 1-MFMA plain-bf16 NT GEMM (A hi, B hi), M=512. PV. K-split 4.
// ---------------------------------------------------------------------------
__global__ __launch_bounds__(256) void mfma_nt1_kernel(
    const ushort* __restrict__ Ah,
    const ushort* __restrict__ Bh,
    float* __restrict__ Cp, int lda, int ldb, int Nout, int kchunk, int bstride)
{
    __shared__ alignas(16) ushort lA[64][40];
    __shared__ alignas(16) ushort lB[64][40];
    const int t = threadIdx.x;
    const int m0 = blockIdx.y * 64, n0 = blockIdx.x * 64, kz = blockIdx.z;
    const int k0 = kz * kchunk;
    const int batch = m0 >> 7;
    const ushort* bhp = Bh + (size_t)batch * bstride;
    const int srow = t >> 2, skc = (t & 3) * 8;
    const int lane = t & 63, w = t >> 6;
    const int wm = (w >> 1) * 32, wn = (w & 1) * 32;
    const int fr = lane & 15, fg = (lane >> 4) * 8;

    f32x4 acc00 = {0,0,0,0}, acc01 = {0,0,0,0}, acc10 = {0,0,0,0}, acc11 = {0,0,0,0};

    for (int kb = k0; kb < k0 + kchunk; kb += 32) {
        *(uint4*)&lA[srow][skc] = *(const uint4*)(Ah  + (size_t)(m0+srow)*lda + kb + skc);
        *(uint4*)&lB[srow][skc] = *(const uint4*)(bhp + (size_t)(n0+srow)*ldb + kb + skc);
        __syncthreads();
        bf16x8 ah0 = *(const bf16x8*)&lA[wm + fr     ][fg];
        bf16x8 ah1 = *(const bf16x8*)&lA[wm + 16 + fr][fg];
        bf16x8 bh0 = *(const bf16x8*)&lB[wn + fr     ][fg];
        bf16x8 bh1 = *(const bf16x8*)&lB[wn + 16 + fr][fg];
        acc00 = MFMA16(ah0, bh0, acc00);
        acc01 = MFMA16(ah0, bh1, acc01);
        acc10 = MFMA16(ah1, bh0, acc10);
        acc11 = MFMA16(ah1, bh1, acc11);
        __syncthreads();
    }
    float* o = Cp + (size_t)kz * 512 * Nout;
    const int orow = (lane >> 4) * 4;
    #pragma unroll
    for (int r2 = 0; r2 < 4; ++r2) {
        o[(size_t)(m0+wm+orow+r2)*Nout      + n0+wn+fr]      = acc00[r2];
        o[(size_t)(m0+wm+orow+r2)*Nout      + n0+wn+16+fr]   = acc01[r2];
        o[(size_t)(m0+wm+16+orow+r2)*Nout   + n0+wn+fr]      = acc10[r2];
        o[(size_t)(m0+wm+16+orow+r2)*Nout   + n0+wn+16+fr]   = acc11[r2];
    }
}

// ---------------------------------------------------------------------------
// [3] Ea = exp2((sum of 4 Ap slices + bq) * K2F)
// ---------------------------------------------------------------------------
__global__ __launch_bounds__(256) void exp_combine_kernel(
    const float* __restrict__ Ap, const float* __restrict__ bias,
    float* __restrict__ E)
{
    int i = blockIdx.x * 256 + threadIdx.x;
    float4 p0 = ((const float4*)Ap)[i];
    float4 p1 = ((const float4*)(Ap + SLICE))[i];
    float4 p2 = ((const float4*)(Ap + 2*SLICE))[i];
    float4 p3 = ((const float4*)(Ap + 3*SLICE))[i];
    float4 bb = ((const float4*)bias)[i & 255];
    float4 r;
    r.x = exp2f((p0.x+p1.x+p2.x+p3.x+bb.x) * K2F);
    r.y = exp2f((p0.y+p1.y+p2.y+p3.y+bb.y) * K2F);
    r.z = exp2f((p0.z+p1.z+p2.z+p3.z+bb.z) * K2F);
    r.w = exp2f((p0.w+p1.w+p2.w+p3.w+bb.w) * K2F);
    ((float4*)E)[i] = r;
}

// ---------------------------------------------------------------------------
// [4] scores v14: as v13 but Sp stored in bf16 (4 MB total).
// 512-thread blocks, 64q x 64k x 128n (two halves, register-prefetched),
// 2x4/thread, QUAD-rcp, ea row-major. Grid 8x8x8 = 512 blocks.
// ---------------------------------------------------------------------------
__global__ __launch_bounds__(512, 4) void score_v14_kernel(
    const float* __restrict__ Ea,   // [512][1024]
    const float* __restrict__ keys,
    const float* __restrict__ watt,
    ushort* __restrict__ Sp)        // [8][512][512] bf16
{
    __shared__ float ea[64][68];    // [q][n]
    __shared__ float ek[64][68];    // [n][k]
    __shared__ float wl[64];
    const int tid = threadIdx.x;
    const int kt = blockIdx.x;      // 0..7
    const int qt = blockIdx.y;      // 0..7
    const int nh = blockIdx.z;      // 0..7
    const int q0 = qt * 64;
    const int b  = qt >> 1;
    const int k0 = b*TK + kt*64;
    const int tx = tid & 15;
    const int ty = tid >> 4;
    const int sq  = tid >> 3;
    const int snc = (tid & 7) * 8;
    float acc[2][4] = {};

    float4 rE0, rE1, rK0, rK1;
    float  rW = 0.f;
    {
        const int nbeg = nh*128;
        const float* ep = Ea + (size_t)(q0 + sq)*NN + nbeg + snc;
        rE0 = *(const float4*)(ep);
        rE1 = *(const float4*)(ep + 4);
        const float* kp = keys + (size_t)(k0 + sq)*NN + nbeg + snc;
        rK0 = *(const float4*)(kp);
        rK1 = *(const float4*)(kp + 4);
        if (tid < 64) rW = watt[nbeg + tid];
    }

    #pragma unroll
    for (int half = 0; half < 2; ++half) {
        if (half) __syncthreads();
        *(float4*)&ea[sq][snc]     = rE0;
        *(float4*)&ea[sq][snc + 4] = rE1;
        ek[snc+0][sq] = exp2f(rK0.x * K2F);
        ek[snc+1][sq] = exp2f(rK0.y * K2F);
        ek[snc+2][sq] = exp2f(rK0.z * K2F);
        ek[snc+3][sq] = exp2f(rK0.w * K2F);
        ek[snc+4][sq] = exp2f(rK1.x * K2F);
        ek[snc+5][sq] = exp2f(rK1.y * K2F);
        ek[snc+6][sq] = exp2f(rK1.z * K2F);
        ek[snc+7][sq] = exp2f(rK1.w * K2F);
        if (tid < 64) wl[tid] = rW;
        __syncthreads();

        if (half == 0) {
            const int nbeg = nh*128 + 64;
            const float* ep = Ea + (size_t)(q0 + sq)*NN + nbeg + snc;
            rE0 = *(const float4*)(ep);
            rE1 = *(const float4*)(ep + 4);
            const float* kp = keys + (size_t)(k0 + sq)*NN + nbeg + snc;
            rK0 = *(const float4*)(kp);
            rK1 = *(const float4*)(kp + 4);
            if (tid < 64) rW = watt[nbeg + tid];
        }

        #pragma unroll 4
        for (int g = 0; g < 16; ++g) {
            float4 a0 = *(const float4*)&ea[ty*2 + 0][4*g];
            float4 a1 = *(const float4*)&ea[ty*2 + 1][4*g];
            float4 f0 = *(const float4*)&ek[4*g+0][tx*4];
            float4 f1 = *(const float4*)&ek[4*g+1][tx*4];
            float4 f2 = *(const float4*)&ek[4*g+2][tx*4];
            float4 f3 = *(const float4*)&ek[4*g+3][tx*4];
            float4 w4 = *(const float4*)&wl[4*g];
            float F0[4] = {f0.x, f0.y, f0.z, f0.w};
            float F1[4] = {f1.x, f1.y, f1.z, f1.w};
            float F2[4] = {f2.x, f2.y, f2.z, f2.w};
            float F3[4] = {f3.x, f3.y, f3.z, f3.w};
            #pragma unroll
            for (int i = 0; i < 2; ++i) {
                const float4 a = i ? a1 : a0;
                #pragma unroll
                for (int j = 0; j < 4; ++j) {
                    float A  = fmaf(a.x, F0[j], 1.0f);
                    float Bv = fmaf(a.y, F1[j], 1.0f);
                    float C  = fmaf(a.z, F2[j], 1.0f);
                    float D  = fmaf(a.w, F3[j], 1.0f);
                    float AB = A * Bv;
                    float CD = C * D;
                    float n01 = fmaf(w4.x, Bv, w4.y * A);
                    float n23 = fmaf(w4.z, D,  w4.w * C);
                    float num = fmaf(n01, CD, n23 * AB);
                    acc[i][j] = fmaf(num, __builtin_amdgcn_rcpf(AB * CD), acc[i][j]);
                }
            }
        }
    }
    ushort* o = Sp + ((size_t)nh*512 + q0 + ty*2)*TK + kt*64 + tx*4;
    #pragma unroll
    for (int i = 0; i < 2; ++i) {
        ushort4 r;
        r.x = bf16_rne(-2.0f*acc[i][0]);
        r.y = bf16_rne(-2.0f*acc[i][1]);
        r.z = bf16_rne(-2.0f*acc[i][2]);
        r.w = bf16_rne(-2.0f*acc[i][3]);
        *(ushort4*)(o + (size_t)i*TK) = r;
    }
}

// ---------------------------------------------------------------------------
// [5] softmax over k of sum_{h<8} Sp[h] (bf16); P f32 (output 1) + Ph (bf16)
// Lane owns contiguous k-octet: k = lane*8 + jj (ushort8 loads).
// ---------------------------------------------------------------------------
__global__ __launch_bounds__(256) void softmax_kernel(
    const ushort* __restrict__ Sp, float* __restrict__ P,
    ushort* __restrict__ Ph)
{
    const int lane = threadIdx.x & 63;
    const int wid  = threadIdx.x >> 6;
    const int row  = blockIdx.x * 4 + wid;
    const size_t S = (size_t)512*512;
    const int kb = lane * 8;
    float v[8] = {0,0,0,0,0,0,0,0};
    #pragma unroll
    for (int h = 0; h < 8; ++h) {
        ushort4 s0 = *(const ushort4*)(Sp + h*S + (size_t)row*TK + kb);
        ushort4 s1 = *(const ushort4*)(Sp + h*S + (size_t)row*TK + kb + 4);
        v[0] += bf16_to_f(s0.x); v[1] += bf16_to_f(s0.y);
        v[2] += bf16_to_f(s0.z); v[3] += bf16_to_f(s0.w);
        v[4] += bf16_to_f(s1.x); v[5] += bf16_to_f(s1.y);
        v[6] += bf16_to_f(s1.z); v[7] += bf16_to_f(s1.w);
    }
    float m = -3.4e38f;
    #pragma unroll
    for (int j = 0; j < 8; ++j) m = fmaxf(m, v[j]);
    #pragma unroll
    for (int off = 32; off; off >>= 1) m = fmaxf(m, __shfl_xor(m, off, 64));
    float sum = 0.f;
    #pragma unroll
    for (int j = 0; j < 8; ++j) { v[j] = exp2f((v[j] - m) * LOG2EF); sum += v[j]; }
    #pragma unroll
    for (int off = 32; off; off >>= 1) sum += __shfl_xor(sum, off, 64);
    float inv = 1.0f / sum;
    float4 p0, p1;
    ushort4 h0, h1;
    p0.x = v[0]*inv; p0.y = v[1]*inv; p0.z = v[2]*inv; p0.w = v[3]*inv;
    p1.x = v[4]*inv; p1.y = v[5]*inv; p1.z = v[6]*inv; p1.w = v[7]*inv;
    h0.x = bf16_rne(p0.x); h0.y = bf16_rne(p0.y); h0.z = bf16_rne(p0.z); h0.w = bf16_rne(p0.w);
    h1.x = bf16_rne(p1.x); h1.y = bf16_rne(p1.y); h1.z = bf16_rne(p1.z); h1.w = bf16_rne(p1.w);
    *(float4*)(P + (size_t)row*TK + kb)     = p0;
    *(float4*)(P + (size_t)row*TK + kb + 4) = p1;
    *(ushort4*)(Ph + (size_t)row*TK + kb)     = h0;
    *(ushort4*)(Ph + (size_t)row*TK + kb + 4) = h1;
}

// ---------------------------------------------------------------------------
// [7] Cx = sum of 4 Ep slices -> hi bf16 only
// ---------------------------------------------------------------------------
__global__ __launch_bounds__(256) void combine_cvt_kernel(
    const float* __restrict__ Ep, ushort* __restrict__ Ch)
{
    int i = blockIdx.x * 256 + threadIdx.x;
    float4 p0 = ((const float4*)Ep)[i];
    float4 p1 = ((const float4*)(Ep + SLICE))[i];
    float4 p2 = ((const float4*)(Ep + 2*SLICE))[i];
    float4 p3 = ((const float4*)(Ep + 3*SLICE))[i];
    float4 s = {p0.x+p1.x+p2.x+p3.x, p0.y+p1.y+p2.y+p3.y,
                p0.z+p1.z+p2.z+p3.z, p0.w+p1.w+p2.w+p3.w};
    ushort4 hh;
    hh.x = bf16_rne(s.x); hh.y = bf16_rne(s.y);
    hh.z = bf16_rne(s.z); hh.w = bf16_rne(s.w);
    ((ushort4*)Ch)[i] = hh;
}

// ---------------------------------------------------------------------------
// [8] out-GEMM: A = [Qh | Cxh] (hi only), B = Woh (1-MFMA). K=2048/4.
// ---------------------------------------------------------------------------
__global__ __launch_bounds__(256) void mfma_out_kernel(
    const ushort* __restrict__ Qh,
    const ushort* __restrict__ Cxh,
    const ushort* __restrict__ Wh,  // [1024][2048] hi
    float* __restrict__ Fp)
{
    __shared__ alignas(16) ushort lA[64][40];
    __shared__ alignas(16) ushort lB[64][40];
    const int t = threadIdx.x;
    const int m0 = blockIdx.y * 64, n0 = blockIdx.x * 64, kz = blockIdx.z;
    const ushort* ah_p = (kz < 2) ? Qh : Cxh;
    const int akoff = (kz & 1) * 512;
    const int bkoff = kz * 512;
    const int srow = t >> 2, skc = (t & 3) * 8;
    const int lane = t & 63, w = t >> 6;
    const int wm = (w >> 1) * 32, wn = (w & 1) * 32;
    const int fr = lane & 15, fg = (lane >> 4) * 8;

    f32x4 acc00 = {0,0,0,0}, acc01 = {0,0,0,0}, acc10 = {0,0,0,0}, acc11 = {0,0,0,0};

    for (int kk = 0; kk < 512; kk += 32) {
        size_t aoff = (size_t)(m0+srow)*1024 + akoff + kk + skc;
        *(uint4*)&lA[srow][skc] = *(const uint4*)(ah_p + aoff);
        *(uint4*)&lB[srow][skc] =
            *(const uint4*)(Wh + (size_t)(n0+srow)*2048 + bkoff + kk + skc);
        __syncthreads();
        bf16x8 ah0 = *(const bf16x8*)&lA[wm + fr     ][fg];
        bf16x8 ah1 = *(const bf16x8*)&lA[wm + 16 + fr][fg];
        bf16x8 bh0 = *(const bf16x8*)&lB[wn + fr     ][fg];
        bf16x8 bh1 = *(const bf16x8*)&lB[wn + 16 + fr][fg];
        acc00 = MFMA16(ah0, bh0, acc00);
        acc01 = MFMA16(ah0, bh1, acc01);
        acc10 = MFMA16(ah1, bh0, acc10);
        acc11 = MFMA16(ah1, bh1, acc11);
        __syncthreads();
    }
    float* o = Fp + (size_t)kz * SLICE;
    const int orow = (lane >> 4) * 4;
    #pragma unroll
    for (int r2 = 0; r2 < 4; ++r2) {
        o[(size_t)(m0+wm+orow+r2)*1024    + n0+wn+fr]    = acc00[r2];
        o[(size_t)(m0+wm+orow+r2)*1024    + n0+wn+16+fr] = acc01[r2];
        o[(size_t)(m0+wm+16+orow+r2)*1024 + n0+wn+fr]    = acc10[r2];
        o[(size_t)(m0+wm+16+orow+r2)*1024 + n0+wn+16+fr] = acc11[r2];
    }
}

// ---------------------------------------------------------------------------
// [9] out = tanh(sum Fp + bias)
// ---------------------------------------------------------------------------
__global__ __launch_bounds__(256) void tanh_combine_kernel(
    const float* __restrict__ Fp, const float* __restrict__ bias,
    float* __restrict__ out)
{
    int i = blockIdx.x * 256 + threadIdx.x;
    const size_t S = (size_t)B_*TQ*OS;
    float4 p0 = ((const float4*)Fp)[i];
    float4 p1 = ((const float4*)(Fp + S))[i];
    float4 p2 = ((const float4*)(Fp + 2*S))[i];
    float4 p3 = ((const float4*)(Fp + 3*S))[i];
    float4 bb = ((const float4*)bias)[i & 255];
    float4 r;
    r.x = tanhf(p0.x + p1.x + p2.x + p3.x + bb.x);
    r.y = tanhf(p0.y + p1.y + p2.y + p3.y + bb.y);
    r.z = tanhf(p0.z + p1.z + p2.z + p3.z + bb.z);
    r.w = tanhf(p0.w + p1.w + p2.w + p3.w + bb.w);
    ((float4*)out)[i] = r;
}

// ---------------------------------------------------------------------------
extern "C" void kernel_launch(void* const* d_in, const int* in_sizes, int n_in,
                              void* d_out, int out_size, void* d_ws, size_t ws_size,
                              hipStream_t stream)
{
    const float* query  = (const float*)d_in[0];
    const float* keys   = (const float*)d_in[1];
    const float* values = (const float*)d_in[2];
    const float* Wq     = (const float*)d_in[3];
    const float* bq     = (const float*)d_in[4];
    const float* watt   = (const float*)d_in[5];
    // d_in[6] = b_att: dropped (softmax shift-invariance)
    const float* Wout   = (const float*)d_in[7];
    const float* bout   = (const float*)d_in[8];

    float* out = (float*)d_out;                    // output 0 (524288 f32)
    float* P   = out + (size_t)B_*TQ*OS;           // output 1 (262144 f32)

    char* base = (char*)d_ws;
    const size_t MB = 1u << 20;
    ushort* Qh  = (ushort*)(base +  0*MB);
    ushort* Ql  = (ushort*)(base +  1*MB);
    ushort* Wqh = (ushort*)(base +  2*MB);   // 2 MB (hi only)
    ushort* Woh = (ushort*)(base +  6*MB);   // 4 MB (hi only)
    ushort* Vth = (ushort*)(base + 10*MB);   // 4 MB (hi only)
    float*  Ap  = (float*) (base + 14*MB);   // [4][512][1024] = 8 MB
    float*  Ea  = (float*) (base + 22*MB);   // 2 MB
    ushort* Sp  = (ushort*)(base + 24*MB);   // [8][512][512] bf16 = 4 MB
    ushort* Ph  = (ushort*)(base + 28*MB);   // 0.5 MB
    float*  Ep  = (float*) (base + 29*MB);   // [4][512][1024] = 8 MB
    ushort* Cxh = (ushort*)(base + 37*MB);   // 1 MB
    float*  Fp  = (float*) (base + 39*MB);   // [4][512][1024] = 8 MB

    // [1] conversions + V transpose (Wq/Wout/V hi-only; Q hi/lo)
    cvt_all_kernel<<<dim3(4096), dim3(256), 0, stream>>>(
        query, Wq, Wout, values, Qh, Ql, Wqh, Woh, Vth);
    // [2] A-GEMM partials: Q @ Wq^T (2-MFMA, A hi/lo; K=1024 split 4)
    mfma_nt2_kernel<<<dim3(16, 8, 4), dim3(256), 0, stream>>>(
        Qh, Ql, Wqh, Ap, 1024, 1024, 1024, 256, 0);
    // [3] Ea = exp(2*(sum Ap + bq))
    exp_combine_kernel<<<dim3(512), dim3(256), 0, stream>>>(Ap, bq, Ea);
    // [4] scores v14 (quad-rcp, register prefetch, bf16 Sp)
    score_v14_kernel<<<dim3(8, 8, 8), dim3(512), 0, stream>>>(Ea, keys, watt, Sp);
    // [5] softmax -> P (output 1) + Ph (bf16 hi)
    softmax_kernel<<<dim3(128), dim3(256), 0, stream>>>(Sp, P, Ph);
    // [6] PV partials: P @ V (1-MFMA bf16, per-batch, K=512 split 4)
    mfma_nt1_kernel<<<dim3(16, 8, 4), dim3(256), 0, stream>>>(
        Ph, Vth, Ep, 512, 512, 1024, 128, VS*TK);
    // [7] Cx = sum Ep -> hi bf16
    combine_cvt_kernel<<<dim3(512), dim3(256), 0, stream>>>(Ep, Cxh);
    // [8] out-GEMM partials (1-MFMA bf16; K=2048 split 4)
    mfma_out_kernel<<<dim3(16, 8, 4), dim3(256), 0, stream>>>(
        Qh, Cxh, Woh, Fp);
    // [9] out = tanh(sum + bout)
    tanh_combine_kernel<<<dim3(512), dim3(256), 0, stream>>>(Fp, bout, out);
}

// Round 22
// 73.249 us; speedup vs baseline: 1.0248x; 1.0248x over previous
//
#include <hip/hip_runtime.h>
#include <math.h>

static constexpr int B_  = 4;
static constexpr int TQ  = 128;
static constexpr int TK  = 512;
static constexpr int NN  = 1024;
static constexpr int QS  = 1024;
static constexpr int VS  = 1024;
static constexpr int OS  = 1024;

#define K2F    2.8853900817779268f   // 2*log2(e)
#define LOG2EF 1.4426950408889634f
#define SLICE  524288                // 512*1024

typedef __attribute__((ext_vector_type(8))) short bf16x8;
typedef __attribute__((ext_vector_type(4))) float f32x4;

#define MFMA16(a,b,c) __builtin_amdgcn_mfma_f32_16x16x32_bf16((a),(b),(c),0,0,0)

__device__ __forceinline__ ushort bf16_rne(float x) {
    uint u = __float_as_uint(x);
    u += 0x7FFFu + ((u >> 16) & 1u);
    return (ushort)(u >> 16);
}
__device__ __forceinline__ void split2(float x, ushort& h, ushort& l) {
    ushort hh = bf16_rne(x);
    float hv = __uint_as_float((uint)hh << 16);
    h = hh;
    l = bf16_rne(x - hv);
}

// ---------------------------------------------------------------------------
// [1] conversion: Q -> hi/lo, Wq -> hi, Wout -> hi, V transpose -> hi only
// blocks: [0,512) Q, [512,1536) Wq(hi), [1536,3584) Wout(hi), [3584,4096) V-T
// ---------------------------------------------------------------------------
__global__ __launch_bounds__(256) void cvt_all_kernel(
    const float* __restrict__ Q, const float* __restrict__ Wq,
    const float* __restrict__ Wo, const float* __restrict__ V,
    ushort* __restrict__ Qh, ushort* __restrict__ Ql,
    ushort* __restrict__ Wqh,
    ushort* __restrict__ Woh,
    ushort* __restrict__ Vth)
{
    __shared__ float tile[64][65];
    const int bid = blockIdx.x;
    const int t = threadIdx.x;
    if (bid < 3584) {
        if (bid < 512) {
            int idx = bid*256 + t;
            float4 v = ((const float4*)Q)[idx];
            ushort4 hh, ll;
            split2(v.x, hh.x, ll.x); split2(v.y, hh.y, ll.y);
            split2(v.z, hh.z, ll.z); split2(v.w, hh.w, ll.w);
            ((ushort4*)Qh)[idx] = hh;
            ((ushort4*)Ql)[idx] = ll;
        } else {
            const float* src; ushort* h; int idx;
            if (bid < 1536) { src = Wq; h = Wqh; idx = (bid-512)*256 + t; }
            else            { src = Wo; h = Woh; idx = (bid-1536)*256 + t; }
            float4 v = ((const float4*)src)[idx];
            ushort4 hh;
            hh.x = bf16_rne(v.x); hh.y = bf16_rne(v.y);
            hh.z = bf16_rne(v.z); hh.w = bf16_rne(v.w);
            ((ushort4*)h)[idx] = hh;
        }
        return;
    }
    const int vid = bid - 3584;
    const int v0 = (vid & 15) * 64;
    const int k0 = ((vid >> 4) & 7) * 64;
    const int b  = vid >> 7;
    const float* src = V + ((size_t)b*TK + k0)*VS + v0;
    #pragma unroll
    for (int p = 0; p < 4; ++p) {
        int r = (t >> 4) + p*16, c = (t & 15) * 4;
        float4 vv = *(const float4*)(src + (size_t)r*VS + c);
        tile[r][c] = vv.x; tile[r][c+1] = vv.y; tile[r][c+2] = vv.z; tile[r][c+3] = vv.w;
    }
    __syncthreads();
    ushort* dh = Vth + (size_t)b*(VS*TK) + (size_t)v0*TK + k0;
    #pragma unroll
    for (int p = 0; p < 4; ++p) {
        int vr = (t >> 4) + p*16, kc = (t & 15) * 4;
        ushort4 hh;
        hh.x = bf16_rne(tile[kc+0][vr]);
        hh.y = bf16_rne(tile[kc+1][vr]);
        hh.z = bf16_rne(tile[kc+2][vr]);
        hh.w = bf16_rne(tile[kc+3][vr]);
        *(ushort4*)(dh + (size_t)vr*TK + kc) = hh;
    }
}

// ---------------------------------------------------------------------------
// [2] 2-MFMA NT GEMM (A hi/lo, B hi only), M=512. A-GEMM. K-split 4.
// ---------------------------------------------------------------------------
__global__ __launch_bounds__(256) void mfma_nt2_kernel(
    const ushort* __restrict__ Ah, const ushort* __restrict__ Al,
    const ushort* __restrict__ Bh,
    float* __restrict__ Cp, int lda, int ldb, int Nout, int kchunk, int bstride)
{
    __shared__ alignas(16) ushort lA[2][64][40];
    __shared__ alignas(16) ushort lB[64][40];
    const int t = threadIdx.x;
    const int m0 = blockIdx.y * 64, n0 = blockIdx.x * 64, kz = blockIdx.z;
    const int k0 = kz * kchunk;
    const int batch = m0 >> 7;
    const ushort* bhp = Bh + (size_t)batch * bstride;
    const int srow = t >> 2, skc = (t & 3) * 8;
    const int lane = t & 63, w = t >> 6;
    const int wm = (w >> 1) * 32, wn = (w & 1) * 32;
    const int fr = lane & 15, fg = (lane >> 4) * 8;

    f32x4 acc00 = {0,0,0,0}, acc01 = {0,0,0,0}, acc10 = {0,0,0,0}, acc11 = {0,0,0,0};

    for (int kb = k0; kb < k0 + kchunk; kb += 32) {
        *(uint4*)&lA[0][srow][skc] = *(const uint4*)(Ah  + (size_t)(m0+srow)*lda + kb + skc);
        *(uint4*)&lA[1][srow][skc] = *(const uint4*)(Al  + (size_t)(m0+srow)*lda + kb + skc);
        *(uint4*)&lB[srow][skc]    = *(const uint4*)(bhp + (size_t)(n0+srow)*ldb + kb + skc);
        __syncthreads();
        bf16x8 ah0 = *(const bf16x8*)&lA[0][wm + fr     ][fg];
        bf16x8 ah1 = *(const bf16x8*)&lA[0][wm + 16 + fr][fg];
        bf16x8 al0 = *(const bf16x8*)&lA[1][wm + fr     ][fg];
        bf16x8 al1 = *(const bf16x8*)&lA[1][wm + 16 + fr][fg];
        bf16x8 bh0 = *(const bf16x8*)&lB[wn + fr     ][fg];
        bf16x8 bh1 = *(const bf16x8*)&lB[wn + 16 + fr][fg];
        acc00 = MFMA16(ah0, bh0, acc00);
        acc00 = MFMA16(al0, bh0, acc00);
        acc01 = MFMA16(ah0, bh1, acc01);
        acc01 = MFMA16(al0, bh1, acc01);
        acc10 = MFMA16(ah1, bh0, acc10);
        acc10 = MFMA16(al1, bh0, acc10);
        acc11 = MFMA16(ah1, bh1, acc11);
        acc11 = MFMA16(al1, bh1, acc11);
        __syncthreads();
    }
    float* o = Cp + (size_t)kz * 512 * Nout;
    const int orow = (lane >> 4) * 4;
    #pragma unroll
    for (int r2 = 0; r2 < 4; ++r2) {
        o[(size_t)(m0+wm+orow+r2)*Nout      + n0+wn+fr]      = acc00[r2];
        o[(size_t)(m0+wm+orow+r2)*Nout      + n0+wn+16+fr]   = acc01[r2];
        o[(size_t)(m0+wm+16+orow+r2)*Nout   + n0+wn+fr]      = acc10[r2];
        o[(size_t)(m0+wm+16+orow+r2)*Nout   + n0+wn+16+fr]   = acc11[r2];
    }
}

// ---------------------------------------------------------------------------
// [6] 1-MFMA plain-bf16 NT GEMM (A hi, B hi), M=512. PV. K-split 4.
// ---------------------------------------------------------------------------
__global__ __launch_bounds__(256) void mfma_nt1_kernel(
    const ushort* __restrict__ Ah,
    const ushort* __restrict__ Bh,
    float* __restrict__ Cp, int lda, int ldb, int Nout, int kchunk, int bstride)
{
    __shared__ alignas(16) ushort lA[64][40];
    __shared__ alignas(16) ushort lB[64][40];
    const int t = threadIdx.x;
    const int m0 = blockIdx.y * 64, n0 = blockIdx.x * 64, kz = blockIdx.z;
    const int k0 = kz * kchunk;
    const int batch = m0 >> 7;
    const ushort* bhp = Bh + (size_t)batch * bstride;
    const int srow = t >> 2, skc = (t & 3) * 8;
    const int lane = t & 63, w = t >> 6;
    const int wm = (w >> 1) * 32, wn = (w & 1) * 32;
    const int fr = lane & 15, fg = (lane >> 4) * 8;

    f32x4 acc00 = {0,0,0,0}, acc01 = {0,0,0,0}, acc10 = {0,0,0,0}, acc11 = {0,0,0,0};

    for (int kb = k0; kb < k0 + kchunk; kb += 32) {
        *(uint4*)&lA[srow][skc] = *(const uint4*)(Ah  + (size_t)(m0+srow)*lda + kb + skc);
        *(uint4*)&lB[srow][skc] = *(const uint4*)(bhp + (size_t)(n0+srow)*ldb + kb + skc);
        __syncthreads();
        bf16x8 ah0 = *(const bf16x8*)&lA[wm + fr     ][fg];
        bf16x8 ah1 = *(const bf16x8*)&lA[wm + 16 + fr][fg];
        bf16x8 bh0 = *(const bf16x8*)&lB[wn + fr     ][fg];
        bf16x8 bh1 = *(const bf16x8*)&lB[wn + 16 + fr][fg];
        acc00 = MFMA16(ah0, bh0, acc00);
        acc01 = MFMA16(ah0, bh1, acc01);
        acc10 = MFMA16(ah1, bh0, acc10);
        acc11 = MFMA16(ah1, bh1, acc11);
        __syncthreads();
    }
    float* o = Cp + (size_t)kz * 512 * Nout;
    const int orow = (lane >> 4) * 4;
    #pragma unroll
    for (int r2 = 0; r2 < 4; ++r2) {
        o[(size_t)(m0+wm+orow+r2)*Nout      + n0+wn+fr]      = acc00[r2];
        o[(size_t)(m0+wm+orow+r2)*Nout      + n0+wn+16+fr]   = acc01[r2];
        o[(size_t)(m0+wm+16+orow+r2)*Nout   + n0+wn+fr]      = acc10[r2];
        o[(size_t)(m0+wm+16+orow+r2)*Nout   + n0+wn+16+fr]   = acc11[r2];
    }
}

// ---------------------------------------------------------------------------
// [3] Ea = exp2((sum of 4 Ap slices + bq) * K2F)
// ---------------------------------------------------------------------------
__global__ __launch_bounds__(256) void exp_combine_kernel(
    const float* __restrict__ Ap, const float* __restrict__ bias,
    float* __restrict__ E)
{
    int i = blockIdx.x * 256 + threadIdx.x;
    float4 p0 = ((const float4*)Ap)[i];
    float4 p1 = ((const float4*)(Ap + SLICE))[i];
    float4 p2 = ((const float4*)(Ap + 2*SLICE))[i];
    float4 p3 = ((const float4*)(Ap + 3*SLICE))[i];
    float4 bb = ((const float4*)bias)[i & 255];
    float4 r;
    r.x = exp2f((p0.x+p1.x+p2.x+p3.x+bb.x) * K2F);
    r.y = exp2f((p0.y+p1.y+p2.y+p3.y+bb.y) * K2F);
    r.z = exp2f((p0.z+p1.z+p2.z+p3.z+bb.z) * K2F);
    r.w = exp2f((p0.w+p1.w+p2.w+p3.w+bb.w) * K2F);
    ((float4*)E)[i] = r;
}

// ---------------------------------------------------------------------------
// [4] scores v13: 512-thread blocks, 64q x 64k x 128n (two 64-n halves,
// register-prefetched), 2x4/thread, QUAD-rcp. ea row-major [q][n] (b128
// broadcast reads + b128 staged writes); ek [n][k]. Grid 8x8x8 = 512 blocks.
// ---------------------------------------------------------------------------
__global__ __launch_bounds__(512, 4) void score_v13_kernel(
    const float* __restrict__ Ea,   // [512][1024]
    const float* __restrict__ keys,
    const float* __restrict__ watt,
    float* __restrict__ Sp)         // [8][512][512]
{
    __shared__ float ea[64][68];    // [q][n]
    __shared__ float ek[64][68];    // [n][k]
    __shared__ float wl[64];
    const int tid = threadIdx.x;
    const int kt = blockIdx.x;      // 0..7
    const int qt = blockIdx.y;      // 0..7
    const int nh = blockIdx.z;      // 0..7
    const int q0 = qt * 64;
    const int b  = qt >> 1;
    const int k0 = b*TK + kt*64;
    const int tx = tid & 15;
    const int ty = tid >> 4;
    const int sq  = tid >> 3;       // staging row (q for ea, k for ek)
    const int snc = (tid & 7) * 8;  // staging n offset
    float acc[2][4] = {};

    // prefetch registers (half operands)
    float4 rE0, rE1, rK0, rK1;
    float  rW = 0.f;
    {   // load half 0
        const int nbeg = nh*128;
        const float* ep = Ea + (size_t)(q0 + sq)*NN + nbeg + snc;
        rE0 = *(const float4*)(ep);
        rE1 = *(const float4*)(ep + 4);
        const float* kp = keys + (size_t)(k0 + sq)*NN + nbeg + snc;
        rK0 = *(const float4*)(kp);
        rK1 = *(const float4*)(kp + 4);
        if (tid < 64) rW = watt[nbeg + tid];
    }

    #pragma unroll
    for (int half = 0; half < 2; ++half) {
        if (half) __syncthreads();          // all waves done with prev LDS
        // stage regs -> LDS
        *(float4*)&ea[sq][snc]     = rE0;
        *(float4*)&ea[sq][snc + 4] = rE1;
        ek[snc+0][sq] = exp2f(rK0.x * K2F);
        ek[snc+1][sq] = exp2f(rK0.y * K2F);
        ek[snc+2][sq] = exp2f(rK0.z * K2F);
        ek[snc+3][sq] = exp2f(rK0.w * K2F);
        ek[snc+4][sq] = exp2f(rK1.x * K2F);
        ek[snc+5][sq] = exp2f(rK1.y * K2F);
        ek[snc+6][sq] = exp2f(rK1.z * K2F);
        ek[snc+7][sq] = exp2f(rK1.w * K2F);
        if (tid < 64) wl[tid] = rW;
        __syncthreads();

        if (half == 0) {   // issue next-half loads; land during compute
            const int nbeg = nh*128 + 64;
            const float* ep = Ea + (size_t)(q0 + sq)*NN + nbeg + snc;
            rE0 = *(const float4*)(ep);
            rE1 = *(const float4*)(ep + 4);
            const float* kp = keys + (size_t)(k0 + sq)*NN + nbeg + snc;
            rK0 = *(const float4*)(kp);
            rK1 = *(const float4*)(kp + 4);
            if (tid < 64) rW = watt[nbeg + tid];
        }

        #pragma unroll 4
        for (int g = 0; g < 16; ++g) {
            float4 a0 = *(const float4*)&ea[ty*2 + 0][4*g];   // (E0,E1,E2,E3) for q-row 0
            float4 a1 = *(const float4*)&ea[ty*2 + 1][4*g];   // ... for q-row 1
            float4 f0 = *(const float4*)&ek[4*g+0][tx*4];
            float4 f1 = *(const float4*)&ek[4*g+1][tx*4];
            float4 f2 = *(const float4*)&ek[4*g+2][tx*4];
            float4 f3 = *(const float4*)&ek[4*g+3][tx*4];
            float4 w4 = *(const float4*)&wl[4*g];
            float F0[4] = {f0.x, f0.y, f0.z, f0.w};
            float F1[4] = {f1.x, f1.y, f1.z, f1.w};
            float F2[4] = {f2.x, f2.y, f2.z, f2.w};
            float F3[4] = {f3.x, f3.y, f3.z, f3.w};
            #pragma unroll
            for (int i = 0; i < 2; ++i) {
                const float4 a = i ? a1 : a0;
                #pragma unroll
                for (int j = 0; j < 4; ++j) {
                    float A  = fmaf(a.x, F0[j], 1.0f);
                    float Bv = fmaf(a.y, F1[j], 1.0f);
                    float C  = fmaf(a.z, F2[j], 1.0f);
                    float D  = fmaf(a.w, F3[j], 1.0f);
                    float AB = A * Bv;
                    float CD = C * D;
                    float n01 = fmaf(w4.x, Bv, w4.y * A);
                    float n23 = fmaf(w4.z, D,  w4.w * C);
                    float num = fmaf(n01, CD, n23 * AB);
                    acc[i][j] = fmaf(num, __builtin_amdgcn_rcpf(AB * CD), acc[i][j]);
                }
            }
        }
    }
    float* o = Sp + ((size_t)nh*512 + q0 + ty*2)*TK + kt*64 + tx*4;
    #pragma unroll
    for (int i = 0; i < 2; ++i) {
        float4 r = {-2.0f*acc[i][0], -2.0f*acc[i][1], -2.0f*acc[i][2], -2.0f*acc[i][3]};
        *(float4*)(o + (size_t)i*TK) = r;
    }
}

// ---------------------------------------------------------------------------
// [5] softmax over k of sum_{h<8} Sp[h]; P f32 (output 1) + Ph (bf16)
// ---------------------------------------------------------------------------
__global__ __launch_bounds__(256) void softmax_kernel(
    const float* __restrict__ Sp, float* __restrict__ P,
    ushort* __restrict__ Ph)
{
    const int lane = threadIdx.x & 63;
    const int wid  = threadIdx.x >> 6;
    const int row  = blockIdx.x * 4 + wid;
    const size_t S = (size_t)512*512;
    float v[8];
    float m = -3.4e38f;
    #pragma unroll
    for (int j = 0; j < 8; ++j) {
        int k = lane + j*64;
        float s = 0.f;
        #pragma unroll
        for (int h = 0; h < 8; ++h)
            s += Sp[h*S + (size_t)row*TK + k];
        v[j] = s;
        m = fmaxf(m, v[j]);
    }
    #pragma unroll
    for (int off = 32; off; off >>= 1) m = fmaxf(m, __shfl_xor(m, off, 64));
    float sum = 0.f;
    #pragma unroll
    for (int j = 0; j < 8; ++j) { v[j] = exp2f((v[j] - m) * LOG2EF); sum += v[j]; }
    #pragma unroll
    for (int off = 32; off; off >>= 1) sum += __shfl_xor(sum, off, 64);
    float inv = 1.0f / sum;
    #pragma unroll
    for (int j = 0; j < 8; ++j) {
        int k = lane + j*64;
        float pv = v[j] * inv;
        P[(size_t)row * TK + k] = pv;
        Ph[(size_t)row * TK + k] = bf16_rne(pv);
    }
}

// ---------------------------------------------------------------------------
// [7] Cx = sum of 4 Ep slices -> hi bf16 only
// ---------------------------------------------------------------------------
__global__ __launch_bounds__(256) void combine_cvt_kernel(
    const float* __restrict__ Ep, ushort* __restrict__ Ch)
{
    int i = blockIdx.x * 256 + threadIdx.x;
    float4 p0 = ((const float4*)Ep)[i];
    float4 p1 = ((const float4*)(Ep + SLICE))[i];
    float4 p2 = ((const float4*)(Ep + 2*SLICE))[i];
    float4 p3 = ((const float4*)(Ep + 3*SLICE))[i];
    float4 s = {p0.x+p1.x+p2.x+p3.x, p0.y+p1.y+p2.y+p3.y,
                p0.z+p1.z+p2.z+p3.z, p0.w+p1.w+p2.w+p3.w};
    ushort4 hh;
    hh.x = bf16_rne(s.x); hh.y = bf16_rne(s.y);
    hh.z = bf16_rne(s.z); hh.w = bf16_rne(s.w);
    ((ushort4*)Ch)[i] = hh;
}

// ---------------------------------------------------------------------------
// [8] out-GEMM: A = [Qh | Cxh] (hi only), B = Woh (1-MFMA). K=2048/4.
// ---------------------------------------------------------------------------
__global__ __launch_bounds__(256) void mfma_out_kernel(
    const ushort* __restrict__ Qh,
    const ushort* __restrict__ Cxh,
    const ushort* __restrict__ Wh,  // [1024][2048] hi
    float* __restrict__ Fp)
{
    __shared__ alignas(16) ushort lA[64][40];
    __shared__ alignas(16) ushort lB[64][40];
    const int t = threadIdx.x;
    const int m0 = blockIdx.y * 64, n0 = blockIdx.x * 64, kz = blockIdx.z;
    const ushort* ah_p = (kz < 2) ? Qh : Cxh;
    const int akoff = (kz & 1) * 512;
    const int bkoff = kz * 512;
    const int srow = t >> 2, skc = (t & 3) * 8;
    const int lane = t & 63, w = t >> 6;
    const int wm = (w >> 1) * 32, wn = (w & 1) * 32;
    const int fr = lane & 15, fg = (lane >> 4) * 8;

    f32x4 acc00 = {0,0,0,0}, acc01 = {0,0,0,0}, acc10 = {0,0,0,0}, acc11 = {0,0,0,0};

    for (int kk = 0; kk < 512; kk += 32) {
        size_t aoff = (size_t)(m0+srow)*1024 + akoff + kk + skc;
        *(uint4*)&lA[srow][skc] = *(const uint4*)(ah_p + aoff);
        *(uint4*)&lB[srow][skc] =
            *(const uint4*)(Wh + (size_t)(n0+srow)*2048 + bkoff + kk + skc);
        __syncthreads();
        bf16x8 ah0 = *(const bf16x8*)&lA[wm + fr     ][fg];
        bf16x8 ah1 = *(const bf16x8*)&lA[wm + 16 + fr][fg];
        bf16x8 bh0 = *(const bf16x8*)&lB[wn + fr     ][fg];
        bf16x8 bh1 = *(const bf16x8*)&lB[wn + 16 + fr][fg];
        acc00 = MFMA16(ah0, bh0, acc00);
        acc01 = MFMA16(ah0, bh1, acc01);
        acc10 = MFMA16(ah1, bh0, acc10);
        acc11 = MFMA16(ah1, bh1, acc11);
        __syncthreads();
    }
    float* o = Fp + (size_t)kz * SLICE;
    const int orow = (lane >> 4) * 4;
    #pragma unroll
    for (int r2 = 0; r2 < 4; ++r2) {
        o[(size_t)(m0+wm+orow+r2)*1024    + n0+wn+fr]    = acc00[r2];
        o[(size_t)(m0+wm+orow+r2)*1024    + n0+wn+16+fr] = acc01[r2];
        o[(size_t)(m0+wm+16+orow+r2)*1024 + n0+wn+fr]    = acc10[r2];
        o[(size_t)(m0+wm+16+orow+r2)*1024 + n0+wn+16+fr] = acc11[r2];
    }
}

// ---------------------------------------------------------------------------
// [9] out = tanh(sum Fp + bias)
// ---------------------------------------------------------------------------
__global__ __launch_bounds__(256) void tanh_combine_kernel(
    const float* __restrict__ Fp, const float* __restrict__ bias,
    float* __restrict__ out)
{
    int i = blockIdx.x * 256 + threadIdx.x;
    const size_t S = (size_t)B_*TQ*OS;
    float4 p0 = ((const float4*)Fp)[i];
    float4 p1 = ((const float4*)(Fp + S))[i];
    float4 p2 = ((const float4*)(Fp + 2*S))[i];
    float4 p3 = ((const float4*)(Fp + 3*S))[i];
    float4 bb = ((const float4*)bias)[i & 255];
    float4 r;
    r.x = tanhf(p0.x + p1.x + p2.x + p3.x + bb.x);
    r.y = tanhf(p0.y + p1.y + p2.y + p3.y + bb.y);
    r.z = tanhf(p0.z + p1.z + p2.z + p3.z + bb.z);
    r.w = tanhf(p0.w + p1.w + p2.w + p3.w + bb.w);
    ((float4*)out)[i] = r;
}

// ---------------------------------------------------------------------------
extern "C" void kernel_launch(void* const* d_in, const int* in_sizes, int n_in,
                              void* d_out, int out_size, void* d_ws, size_t ws_size,
                              hipStream_t stream)
{
    const float* query  = (const float*)d_in[0];
    const float* keys   = (const float*)d_in[1];
    const float* values = (const float*)d_in[2];
    const float* Wq     = (const float*)d_in[3];
    const float* bq     = (const float*)d_in[4];
    const float* watt   = (const float*)d_in[5];
    // d_in[6] = b_att: dropped (softmax shift-invariance)
    const float* Wout   = (const float*)d_in[7];
    const float* bout   = (const float*)d_in[8];

    float* out = (float*)d_out;                    // output 0 (524288 f32)
    float* P   = out + (size_t)B_*TQ*OS;           // output 1 (262144 f32)

    char* base = (char*)d_ws;
    const size_t MB = 1u << 20;
    ushort* Qh  = (ushort*)(base +  0*MB);
    ushort* Ql  = (ushort*)(base +  1*MB);
    ushort* Wqh = (ushort*)(base +  2*MB);   // 2 MB (hi only)
    ushort* Woh = (ushort*)(base +  6*MB);   // 4 MB (hi only)
    ushort* Vth = (ushort*)(base + 10*MB);   // 4 MB (hi only)
    float*  Ap  = (float*) (base + 14*MB);   // [4][512][1024] = 8 MB
    float*  Ea  = (float*) (base + 22*MB);   // 2 MB
    float*  Sp  = (float*) (base + 24*MB);   // [8][512][512] = 8 MB
    ushort* Ph  = (ushort*)(base + 32*MB);   // 0.5 MB (hi only)
    float*  Ep  = (float*) (base + 33*MB);   // [4][512][1024] = 8 MB
    ushort* Cxh = (ushort*)(base + 41*MB);   // 1 MB (hi only)
    float*  Fp  = (float*) (base + 43*MB);   // [4][512][1024] = 8 MB

    // [1] conversions + V transpose (Wq/Wout/V hi-only; Q hi/lo)
    cvt_all_kernel<<<dim3(4096), dim3(256), 0, stream>>>(
        query, Wq, Wout, values, Qh, Ql, Wqh, Woh, Vth);
    // [2] A-GEMM partials: Q @ Wq^T (2-MFMA, A hi/lo; K=1024 split 4)
    mfma_nt2_kernel<<<dim3(16, 8, 4), dim3(256), 0, stream>>>(
        Qh, Ql, Wqh, Ap, 1024, 1024, 1024, 256, 0);
    // [3] Ea = exp(2*(sum Ap + bq))
    exp_combine_kernel<<<dim3(512), dim3(256), 0, stream>>>(Ap, bq, Ea);
    // [4] scores v13 (quad-rcp, row-major ea, register prefetch)
    score_v13_kernel<<<dim3(8, 8, 8), dim3(512), 0, stream>>>(Ea, keys, watt, Sp);
    // [5] softmax -> P (output 1) + Ph (bf16 hi)
    softmax_kernel<<<dim3(128), dim3(256), 0, stream>>>(Sp, P, Ph);
    // [6] PV partials: P @ V (1-MFMA bf16, per-batch, K=512 split 4)
    mfma_nt1_kernel<<<dim3(16, 8, 4), dim3(256), 0, stream>>>(
        Ph, Vth, Ep, 512, 512, 1024, 128, VS*TK);
    // [7] Cx = sum Ep -> hi bf16
    combine_cvt_kernel<<<dim3(512), dim3(256), 0, stream>>>(Ep, Cxh);
    // [8] out-GEMM partials (1-MFMA bf16; K=2048 split 4)
    mfma_out_kernel<<<dim3(16, 8, 4), dim3(256), 0, stream>>>(
        Qh, Cxh, Woh, Fp);
    // [9] out = tanh(sum + bout)
    tanh_combine_kernel<<<dim3(512), dim3(256), 0, stream>>>(Fp, bout, out);
}